// Round 6
// baseline (257.291 us; speedup 1.0000x reference)
//
#include <hip/hip_runtime.h>
#include <hip/hip_fp8.h>

#define NV 4
#define NB 2048
#define ND 512
#define NN 8192
// sim = cos/TEMP, TEMP=0.5 -> scale 2.0

typedef int int8v __attribute__((ext_vector_type(8)));
typedef float floatx4 __attribute__((ext_vector_type(4)));
#define SCALE1 0x7F7F7F7Fu  // E8M0 bytes 127 -> 2^0 = 1.0

// ---------------- normalize: x[N,D] f32 -> xn[N,D] fp8 e4m3 (unit rows) ----
// Also zeros sumexp (4 floats per block) and out (block 0).
__global__ __launch_bounds__(256) void normalize_k(const float* __restrict__ x,
                                                   unsigned char* __restrict__ xn,
                                                   float* __restrict__ sumexp,
                                                   float* __restrict__ out) {
  if (threadIdx.x < 4) sumexp[blockIdx.x * 4 + threadIdx.x] = 0.0f;
  if (blockIdx.x == 0 && threadIdx.x == 0) out[0] = 0.0f;

  const int row = blockIdx.x * 4 + (threadIdx.x >> 6);  // one wave per row
  const int l = threadIdx.x & 63;                        // lane: cols [8l, 8l+8)
  const float4* xr = (const float4*)(x + (size_t)row * ND);
  float4 v0 = xr[l * 2 + 0];
  float4 v1 = xr[l * 2 + 1];
  float ss = v0.x * v0.x + v0.y * v0.y + v0.z * v0.z + v0.w * v0.w +
             v1.x * v1.x + v1.y * v1.y + v1.z * v1.z + v1.w * v1.w;
#pragma unroll
  for (int off = 32; off > 0; off >>= 1) ss += __shfl_xor(ss, off, 64);
  const float inv = 1.0f / fmaxf(sqrtf(ss), 1e-8f);
  union { unsigned char b[8]; uint2 u; } pk;
  pk.b[0] = __hip_fp8_e4m3(v0.x * inv).__x;
  pk.b[1] = __hip_fp8_e4m3(v0.y * inv).__x;
  pk.b[2] = __hip_fp8_e4m3(v0.z * inv).__x;
  pk.b[3] = __hip_fp8_e4m3(v0.w * inv).__x;
  pk.b[4] = __hip_fp8_e4m3(v1.x * inv).__x;
  pk.b[5] = __hip_fp8_e4m3(v1.y * inv).__x;
  pk.b[6] = __hip_fp8_e4m3(v1.z * inv).__x;
  pk.b[7] = __hip_fp8_e4m3(v1.w * inv).__x;
  *(uint2*)(xn + (size_t)row * ND + l * 8) = pk.u;
}

// ---------------- async global->LDS, 16B per lane --------------------------
__device__ __forceinline__ void gl_lds16(const void* g, void* l) {
  __builtin_amdgcn_global_load_lds(
      (const __attribute__((address_space(1))) void*)g,
      (__attribute__((address_space(3))) void*)l, 16, 0, 0);
}

// ---------------- fused sim GEMM + exp/mask epilogue, triangular, fp8-MX ----
// S symmetric: upper-tri 128x128 tiles (rt<=ct), 2080 blocks. fp8 e4m3 inputs,
// mfma_scale_f32_16x16x128_f8f6f4 with unit E8M0 scales. BK=128 -> 4 K-iters.
//
// LDS swizzle (verified R5: zero read conflicts, numerics exact): row r chunk
// c (16 B) at r*128 + (c^(r&7))*16; staging 8-lane runs fetch contiguous
// 128 B row segments (coalesced + DMA-slot compatible).
//
// R5 LESSON: fragments must be loaded ONCE per kt into af[4]/bf[4] (64 VGPRs)
// before the MFMA nest. Loading B inside the mt*nt nest let the unroller keep
// ~16 B-fragments live -> accumulator scratch spill (291 MB WRITE_SIZE, 3%
// MfmaUtil). Union-bitcast the two swizzled 16 B halves, no scalar inserts.
__global__ __launch_bounds__(256, 3) void sim_k(const unsigned char* __restrict__ xn,
                                                float* __restrict__ sumexp,
                                                float* __restrict__ pos) {
  __shared__ unsigned char As[128 * 128];
  __shared__ unsigned char Bs[128 * 128];
  const int tid = threadIdx.x;
  const int w = tid >> 6, l = tid & 63;
  const int m = l & 15, q = l >> 4, s = l & 7;
  const int wr = w >> 1, wc = w & 1;

  // triangular decode: bid -> (rt, ct), rt <= ct; start(r) = r*64 - r(r-1)/2
  const int bid = blockIdx.x;
  int rt = (int)((129.0f - sqrtf(16641.0f - 8.0f * (float)bid)) * 0.5f);
  rt = rt < 0 ? 0 : (rt > 63 ? 63 : rt);
  while (rt > 0 && (rt * 64 - rt * (rt - 1) / 2) > bid) --rt;
  while (rt < 63 && ((rt + 1) * 64 - (rt + 1) * rt / 2) <= bid) ++rt;
  const int ct = rt + (bid - (rt * 64 - rt * (rt - 1) / 2));
  const bool diag = (rt == ct);

  floatx4 acc[4][4] = {};

  const unsigned char* gA = xn + (size_t)rt * 128 * ND;
  const unsigned char* gB = xn + (size_t)ct * 128 * ND;

  // staging lane geometry: rr = l>>3 (row within 8-row window), cc = l&7;
  // lane fetches global chunk (cc ^ rr) so LDS slot cc holds swizzled data.
  const int rr = l >> 3;
  const int swz = ((l & 7) ^ rr) * 16;

  // fragment read offsets (swizzled): row l&15, k-chunks 2q, 2q+1
  const int fo0 = ((2 * q + 0) ^ s) * 16;
  const int fo1 = ((2 * q + 1) ^ s) * 16;

  union Frag { int4 h[2]; int8v v; };

#pragma unroll
  for (int kt = 0; kt < ND / 128; ++kt) {
    const int kb0 = kt * 128;
#pragma unroll
    for (int i = 0; i < 4; ++i) {
      const int v = i * 4 + w;  // window: rows 8v..8v+7 (wave-uniform)
      const size_t grow = (size_t)(v * 8 + rr) * ND + kb0 + swz;
      gl_lds16(gA + grow, As + v * 1024);
      gl_lds16(gB + grow, Bs + v * 1024);
    }
    __syncthreads();
    Frag af[4], bf[4];
#pragma unroll
    for (int t = 0; t < 4; ++t) {
      const unsigned char* pa = As + (wr * 64 + t * 16 + m) * 128;
      const unsigned char* pb = Bs + (wc * 64 + t * 16 + m) * 128;
      af[t].h[0] = *(const int4*)(pa + fo0);
      af[t].h[1] = *(const int4*)(pa + fo1);
      bf[t].h[0] = *(const int4*)(pb + fo0);
      bf[t].h[1] = *(const int4*)(pb + fo1);
    }
#pragma unroll
    for (int mt = 0; mt < 4; ++mt)
#pragma unroll
      for (int nt = 0; nt < 4; ++nt)
        acc[mt][nt] = __builtin_amdgcn_mfma_scale_f32_16x16x128_f8f6f4(
            af[mt].v, bf[nt].v, acc[mt][nt], 0, 0, 0, SCALE1, 0, SCALE1);
    __syncthreads();  // all waves done reading before next overwrite
  }

  // epilogue: s = 2*acc; masked cols ((c-r)%B==0) store pos, skip sums.
  // Row sums always; col sums + pos mirror only on off-diagonal tiles.
  const int r0 = rt * 128 + wr * 64;
  const int c0 = ct * 128 + wc * 64;
  float cs[4] = {0.f, 0.f, 0.f, 0.f};  // per-nt column partials (this lane's q)
#pragma unroll
  for (int mt = 0; mt < 4; ++mt) {
    float rs[4] = {0.f, 0.f, 0.f, 0.f};
#pragma unroll
    for (int nt = 0; nt < 4; ++nt) {
      const int c = c0 + nt * 16 + m;  // C layout: col = lane&15
#pragma unroll
      for (int reg = 0; reg < 4; ++reg) {
        const int r = r0 + mt * 16 + q * 4 + reg;  // row = quad*4 + reg
        const float sv = acc[mt][nt][reg] * 2.0f;
        if (((c - r) & (NB - 1)) == 0) {
          pos[r * NV + (c >> 11)] = sv;  // includes j==i (unused later)
          if (!diag) pos[c * NV + (r >> 11)] = sv;
        } else {
          const float e = __expf(sv);
          rs[reg] += e;
          cs[nt] += e;
        }
      }
    }
    // reduce rows across the 16-lane column dimension (m)
#pragma unroll
    for (int off = 1; off < 16; off <<= 1) {
#pragma unroll
      for (int reg = 0; reg < 4; ++reg) rs[reg] += __shfl_xor(rs[reg], off, 64);
    }
    if (m < 4) atomicAdd(&sumexp[r0 + mt * 16 + q * 4 + m], rs[m]);
  }
  if (!diag) {
    // reduce cols across the 4-quad row dimension (q)
#pragma unroll
    for (int nt = 0; nt < 4; ++nt) {
      cs[nt] += __shfl_xor(cs[nt], 16, 64);
      cs[nt] += __shfl_xor(cs[nt], 32, 64);
    }
    if (q == 0) {
#pragma unroll
      for (int nt = 0; nt < 4; ++nt)
        atomicAdd(&sumexp[c0 + nt * 16 + m], cs[nt]);
    }
  }
}

// ---------------- finalize: scalar loss -------------------------------------
__global__ __launch_bounds__(256) void finalize_k(
    const float* __restrict__ sumexp, const float* __restrict__ pos,
    float* __restrict__ out) {
  const int r = blockIdx.x * 256 + threadIdx.x;
  const float se = sumexp[r];
  const int i = r >> 11;  // view index
  float local = 0.0f;
#pragma unroll
  for (int j = 0; j < NV; ++j) {
    if (j == i) continue;
    const float p = pos[r * NV + j];
    local += logf(__expf(p) + se) - p;  // logaddexp(pos, lse_neg) - pos
  }
  local *= (1.0f / NB);
#pragma unroll
  for (int off = 32; off > 0; off >>= 1) local += __shfl_xor(local, off, 64);
  if ((threadIdx.x & 63) == 0) atomicAdd(out, local);
}

extern "C" void kernel_launch(void* const* d_in, const int* in_sizes, int n_in,
                              void* d_out, int out_size, void* d_ws,
                              size_t ws_size, hipStream_t stream) {
  const float* x = (const float*)d_in[0];
  float* out = (float*)d_out;
  char* ws = (char*)d_ws;
  unsigned char* xn = (unsigned char*)ws;                 // 4 MB fp8
  float* sumexp = (float*)(ws + (size_t)NN * ND);         // 32 KB
  float* pos = (float*)(ws + (size_t)NN * ND + NN * 4);   // 128 KB

  normalize_k<<<NN / 4, 256, 0, stream>>>(x, xn, sumexp, out);
  sim_k<<<64 * 65 / 2, 256, 0, stream>>>(xn, sumexp, pos);
  finalize_k<<<NN / 256, 256, 0, stream>>>(sumexp, pos, out);
}

// Round 7
// 136.855 us; speedup vs baseline: 1.8800x; 1.8800x over previous
//
#include <hip/hip_runtime.h>
#include <hip/hip_fp8.h>

#define NV 4
#define NB 2048
#define ND 512
#define NN 8192
// sim = cos/TEMP, TEMP=0.5 -> scale 2.0

typedef int int8v __attribute__((ext_vector_type(8)));
typedef int int4v __attribute__((ext_vector_type(4)));
typedef float floatx4 __attribute__((ext_vector_type(4)));
#define SCALE1 0x7F7F7F7Fu  // E8M0 bytes 127 -> 2^0 = 1.0

// ---------------- normalize: x[N,D] f32 -> xn[N,D] fp8 e4m3 (unit rows) ----
// Also zeros sumexp (4 floats per block) and out (block 0).
__global__ __launch_bounds__(256) void normalize_k(const float* __restrict__ x,
                                                   unsigned char* __restrict__ xn,
                                                   float* __restrict__ sumexp,
                                                   float* __restrict__ out) {
  if (threadIdx.x < 4) sumexp[blockIdx.x * 4 + threadIdx.x] = 0.0f;
  if (blockIdx.x == 0 && threadIdx.x == 0) out[0] = 0.0f;

  const int row = blockIdx.x * 4 + (threadIdx.x >> 6);  // one wave per row
  const int l = threadIdx.x & 63;                        // lane: cols [8l, 8l+8)
  const float4* xr = (const float4*)(x + (size_t)row * ND);
  float4 v0 = xr[l * 2 + 0];
  float4 v1 = xr[l * 2 + 1];
  float ss = v0.x * v0.x + v0.y * v0.y + v0.z * v0.z + v0.w * v0.w +
             v1.x * v1.x + v1.y * v1.y + v1.z * v1.z + v1.w * v1.w;
#pragma unroll
  for (int off = 32; off > 0; off >>= 1) ss += __shfl_xor(ss, off, 64);
  const float inv = 1.0f / fmaxf(sqrtf(ss), 1e-8f);
  union { unsigned char b[8]; uint2 u; } pk;
  pk.b[0] = __hip_fp8_e4m3(v0.x * inv).__x;
  pk.b[1] = __hip_fp8_e4m3(v0.y * inv).__x;
  pk.b[2] = __hip_fp8_e4m3(v0.z * inv).__x;
  pk.b[3] = __hip_fp8_e4m3(v0.w * inv).__x;
  pk.b[4] = __hip_fp8_e4m3(v1.x * inv).__x;
  pk.b[5] = __hip_fp8_e4m3(v1.y * inv).__x;
  pk.b[6] = __hip_fp8_e4m3(v1.z * inv).__x;
  pk.b[7] = __hip_fp8_e4m3(v1.w * inv).__x;
  *(uint2*)(xn + (size_t)row * ND + l * 8) = pk.u;
}

// ---------------- async global->LDS, 16B per lane --------------------------
__device__ __forceinline__ void gl_lds16(const void* g, void* l) {
  __builtin_amdgcn_global_load_lds(
      (const __attribute__((address_space(1))) void*)g,
      (__attribute__((address_space(3))) void*)l, 16, 0, 0);
}

// ---------------- fused sim GEMM + exp/mask epilogue, triangular, fp8-MX ----
// S symmetric: upper-tri 128x128 tiles (rt<=ct), 2080 blocks. fp8 e4m3 inputs,
// mfma_scale_f32_16x16x128_f8f6f4 with unit E8M0 scales. BK=128 -> 4 K-iters.
//
// LDS swizzle (verified: zero read conflicts, numerics exact): row r chunk
// c (16 B) at r*128 + (c^(r&7))*16; staging 8-lane runs fetch contiguous
// 128 B row segments (coalesced + DMA-slot compatible).
//
// R5/R6 LESSON (291 MB scratch write, MfmaUtil 3%): the scaled-MFMA path
// spilled. Defenses here: (1) NO min-waves clamp in __launch_bounds__ — the
// (256,3) VGPR cap (~168) could not hold acc(64)+frags(64)+addr if the
// scaled-MFMA acc stays in arch VGPRs (unlike plain bf16 MFMA which uses
// AGPRs); (2) operands built with __builtin_shufflevector over ext-vector
// loads — pure SSA, no union/alloca, SROA-proof.
__global__ __launch_bounds__(256) void sim_k(const unsigned char* __restrict__ xn,
                                             float* __restrict__ sumexp,
                                             float* __restrict__ pos) {
  __shared__ unsigned char As[128 * 128];
  __shared__ unsigned char Bs[128 * 128];
  const int tid = threadIdx.x;
  const int w = tid >> 6, l = tid & 63;
  const int m = l & 15, q = l >> 4, s = l & 7;
  const int wr = w >> 1, wc = w & 1;

  // triangular decode: bid -> (rt, ct), rt <= ct; start(r) = r*64 - r(r-1)/2
  const int bid = blockIdx.x;
  int rt = (int)((129.0f - sqrtf(16641.0f - 8.0f * (float)bid)) * 0.5f);
  rt = rt < 0 ? 0 : (rt > 63 ? 63 : rt);
  while (rt > 0 && (rt * 64 - rt * (rt - 1) / 2) > bid) --rt;
  while (rt < 63 && ((rt + 1) * 64 - (rt + 1) * rt / 2) <= bid) ++rt;
  const int ct = rt + (bid - (rt * 64 - rt * (rt - 1) / 2));
  const bool diag = (rt == ct);

  floatx4 acc[4][4] = {};

  const unsigned char* gA = xn + (size_t)rt * 128 * ND;
  const unsigned char* gB = xn + (size_t)ct * 128 * ND;

  // staging lane geometry: rr = l>>3 (row within 8-row window), cc = l&7;
  // lane fetches global chunk (cc ^ rr) so LDS slot cc holds swizzled data.
  const int rr = l >> 3;
  const int swz = ((l & 7) ^ rr) * 16;

  // fragment read offsets (swizzled): row l&15, k-chunks 2q, 2q+1
  const int fo0 = ((2 * q + 0) ^ s) * 16;
  const int fo1 = ((2 * q + 1) ^ s) * 16;

#pragma unroll
  for (int kt = 0; kt < ND / 128; ++kt) {
    const int kb0 = kt * 128;
#pragma unroll
    for (int i = 0; i < 4; ++i) {
      const int v = i * 4 + w;  // window: rows 8v..8v+7 (wave-uniform)
      const size_t grow = (size_t)(v * 8 + rr) * ND + kb0 + swz;
      gl_lds16(gA + grow, As + v * 1024);
      gl_lds16(gB + grow, Bs + v * 1024);
    }
    __syncthreads();
    int8v af0, af1, af2, af3, bf0, bf1, bf2, bf3;
    {
      const unsigned char* pa0 = As + (wr * 64 + 0 * 16 + m) * 128;
      const unsigned char* pa1 = As + (wr * 64 + 1 * 16 + m) * 128;
      const unsigned char* pa2 = As + (wr * 64 + 2 * 16 + m) * 128;
      const unsigned char* pa3 = As + (wr * 64 + 3 * 16 + m) * 128;
      const unsigned char* pb0 = Bs + (wc * 64 + 0 * 16 + m) * 128;
      const unsigned char* pb1 = Bs + (wc * 64 + 1 * 16 + m) * 128;
      const unsigned char* pb2 = Bs + (wc * 64 + 2 * 16 + m) * 128;
      const unsigned char* pb3 = Bs + (wc * 64 + 3 * 16 + m) * 128;
      af0 = __builtin_shufflevector(*(const int4v*)(pa0 + fo0),
                                    *(const int4v*)(pa0 + fo1), 0,1,2,3,4,5,6,7);
      af1 = __builtin_shufflevector(*(const int4v*)(pa1 + fo0),
                                    *(const int4v*)(pa1 + fo1), 0,1,2,3,4,5,6,7);
      af2 = __builtin_shufflevector(*(const int4v*)(pa2 + fo0),
                                    *(const int4v*)(pa2 + fo1), 0,1,2,3,4,5,6,7);
      af3 = __builtin_shufflevector(*(const int4v*)(pa3 + fo0),
                                    *(const int4v*)(pa3 + fo1), 0,1,2,3,4,5,6,7);
      bf0 = __builtin_shufflevector(*(const int4v*)(pb0 + fo0),
                                    *(const int4v*)(pb0 + fo1), 0,1,2,3,4,5,6,7);
      bf1 = __builtin_shufflevector(*(const int4v*)(pb1 + fo0),
                                    *(const int4v*)(pb1 + fo1), 0,1,2,3,4,5,6,7);
      bf2 = __builtin_shufflevector(*(const int4v*)(pb2 + fo0),
                                    *(const int4v*)(pb2 + fo1), 0,1,2,3,4,5,6,7);
      bf3 = __builtin_shufflevector(*(const int4v*)(pb3 + fo0),
                                    *(const int4v*)(pb3 + fo1), 0,1,2,3,4,5,6,7);
    }
#define MFMA_ROW(mt, afv)                                                     \
  acc[mt][0] = __builtin_amdgcn_mfma_scale_f32_16x16x128_f8f6f4(              \
      afv, bf0, acc[mt][0], 0, 0, 0, SCALE1, 0, SCALE1);                      \
  acc[mt][1] = __builtin_amdgcn_mfma_scale_f32_16x16x128_f8f6f4(              \
      afv, bf1, acc[mt][1], 0, 0, 0, SCALE1, 0, SCALE1);                      \
  acc[mt][2] = __builtin_amdgcn_mfma_scale_f32_16x16x128_f8f6f4(              \
      afv, bf2, acc[mt][2], 0, 0, 0, SCALE1, 0, SCALE1);                      \
  acc[mt][3] = __builtin_amdgcn_mfma_scale_f32_16x16x128_f8f6f4(              \
      afv, bf3, acc[mt][3], 0, 0, 0, SCALE1, 0, SCALE1)
    MFMA_ROW(0, af0);
    MFMA_ROW(1, af1);
    MFMA_ROW(2, af2);
    MFMA_ROW(3, af3);
#undef MFMA_ROW
    __syncthreads();  // all waves done reading before next overwrite
  }

  // epilogue: s = 2*acc; masked cols ((c-r)%B==0) store pos, skip sums.
  // Row sums always; col sums + pos mirror only on off-diagonal tiles.
  const int r0 = rt * 128 + wr * 64;
  const int c0 = ct * 128 + wc * 64;
  float cs[4] = {0.f, 0.f, 0.f, 0.f};  // per-nt column partials (this lane's q)
#pragma unroll
  for (int mt = 0; mt < 4; ++mt) {
    float rs[4] = {0.f, 0.f, 0.f, 0.f};
#pragma unroll
    for (int nt = 0; nt < 4; ++nt) {
      const int c = c0 + nt * 16 + m;  // C layout: col = lane&15
#pragma unroll
      for (int reg = 0; reg < 4; ++reg) {
        const int r = r0 + mt * 16 + q * 4 + reg;  // row = quad*4 + reg
        const float sv = acc[mt][nt][reg] * 2.0f;
        if (((c - r) & (NB - 1)) == 0) {
          pos[r * NV + (c >> 11)] = sv;  // includes j==i (unused later)
          if (!diag) pos[c * NV + (r >> 11)] = sv;
        } else {
          const float e = __expf(sv);
          rs[reg] += e;
          cs[nt] += e;
        }
      }
    }
    // reduce rows across the 16-lane column dimension (m)
#pragma unroll
    for (int off = 1; off < 16; off <<= 1) {
#pragma unroll
      for (int reg = 0; reg < 4; ++reg) rs[reg] += __shfl_xor(rs[reg], off, 64);
    }
    if (m < 4) atomicAdd(&sumexp[r0 + mt * 16 + q * 4 + m], rs[m]);
  }
  if (!diag) {
    // reduce cols across the 4-quad row dimension (q)
#pragma unroll
    for (int nt = 0; nt < 4; ++nt) {
      cs[nt] += __shfl_xor(cs[nt], 16, 64);
      cs[nt] += __shfl_xor(cs[nt], 32, 64);
    }
    if (q == 0) {
#pragma unroll
      for (int nt = 0; nt < 4; ++nt)
        atomicAdd(&sumexp[c0 + nt * 16 + m], cs[nt]);
    }
  }
}

// ---------------- finalize: scalar loss -------------------------------------
__global__ __launch_bounds__(256) void finalize_k(
    const float* __restrict__ sumexp, const float* __restrict__ pos,
    float* __restrict__ out) {
  const int r = blockIdx.x * 256 + threadIdx.x;
  const float se = sumexp[r];
  const int i = r >> 11;  // view index
  float local = 0.0f;
#pragma unroll
  for (int j = 0; j < NV; ++j) {
    if (j == i) continue;
    const float p = pos[r * NV + j];
    local += logf(__expf(p) + se) - p;  // logaddexp(pos, lse_neg) - pos
  }
  local *= (1.0f / NB);
#pragma unroll
  for (int off = 32; off > 0; off >>= 1) local += __shfl_xor(local, off, 64);
  if ((threadIdx.x & 63) == 0) atomicAdd(out, local);
}

extern "C" void kernel_launch(void* const* d_in, const int* in_sizes, int n_in,
                              void* d_out, int out_size, void* d_ws,
                              size_t ws_size, hipStream_t stream) {
  const float* x = (const float*)d_in[0];
  float* out = (float*)d_out;
  char* ws = (char*)d_ws;
  unsigned char* xn = (unsigned char*)ws;                 // 4 MB fp8
  float* sumexp = (float*)(ws + (size_t)NN * ND);         // 32 KB
  float* pos = (float*)(ws + (size_t)NN * ND + NN * 4);   // 128 KB

  normalize_k<<<NN / 4, 256, 0, stream>>>(x, xn, sumexp, out);
  sim_k<<<64 * 65 / 2, 256, 0, stream>>>(xn, sumexp, pos);
  finalize_k<<<NN / 256, 256, 0, stream>>>(sumexp, pos, out);
}

// Round 8
// 110.446 us; speedup vs baseline: 2.3296x; 1.2391x over previous
//
#include <hip/hip_runtime.h>
#include <hip/hip_fp8.h>

#define NV 4
#define NB 2048
#define ND 512
#define NN 8192
// sim = cos/TEMP, TEMP=0.5 -> scale 2.0

typedef int int8v __attribute__((ext_vector_type(8)));
typedef int int4v __attribute__((ext_vector_type(4)));
typedef float floatx4 __attribute__((ext_vector_type(4)));
#define SCALE1 0x7F7F7F7Fu  // E8M0 bytes 127 -> 2^0 = 1.0

// ---------------- normalize: x[N,D] f32 -> xn[N,D] fp8 e4m3 (unit rows) ----
// Also zeros sumexp (4 floats per block) and out (block 0).
__global__ __launch_bounds__(256) void normalize_k(const float* __restrict__ x,
                                                   unsigned char* __restrict__ xn,
                                                   float* __restrict__ sumexp,
                                                   float* __restrict__ out) {
  if (threadIdx.x < 4) sumexp[blockIdx.x * 4 + threadIdx.x] = 0.0f;
  if (blockIdx.x == 0 && threadIdx.x == 0) out[0] = 0.0f;

  const int row = blockIdx.x * 4 + (threadIdx.x >> 6);  // one wave per row
  const int l = threadIdx.x & 63;                        // lane: cols [8l, 8l+8)
  const float4* xr = (const float4*)(x + (size_t)row * ND);
  float4 v0 = xr[l * 2 + 0];
  float4 v1 = xr[l * 2 + 1];
  float ss = v0.x * v0.x + v0.y * v0.y + v0.z * v0.z + v0.w * v0.w +
             v1.x * v1.x + v1.y * v1.y + v1.z * v1.z + v1.w * v1.w;
#pragma unroll
  for (int off = 32; off > 0; off >>= 1) ss += __shfl_xor(ss, off, 64);
  const float inv = 1.0f / fmaxf(sqrtf(ss), 1e-8f);
  union { unsigned char b[8]; uint2 u; } pk;
  pk.b[0] = __hip_fp8_e4m3(v0.x * inv).__x;
  pk.b[1] = __hip_fp8_e4m3(v0.y * inv).__x;
  pk.b[2] = __hip_fp8_e4m3(v0.z * inv).__x;
  pk.b[3] = __hip_fp8_e4m3(v0.w * inv).__x;
  pk.b[4] = __hip_fp8_e4m3(v1.x * inv).__x;
  pk.b[5] = __hip_fp8_e4m3(v1.y * inv).__x;
  pk.b[6] = __hip_fp8_e4m3(v1.z * inv).__x;
  pk.b[7] = __hip_fp8_e4m3(v1.w * inv).__x;
  *(uint2*)(xn + (size_t)row * ND + l * 8) = pk.u;
}

// ---------------- fused sim GEMM + exp/mask epilogue, triangular, fp8-MX ----
// S symmetric: upper-tri 128x128 tiles (rt<=ct), 2080 blocks. fp8 e4m3 inputs,
// mfma_scale_f32_16x16x128_f8f6f4 with unit E8M0 scales. BK=128 -> 4 K-iters.
//
// R7 LESSON: global_load_lds + vmcnt(0)-drain-before-barrier serialized 32 KB
// of DMA against compute every kt; at 2 blocks/CU nothing hid it (MfmaUtil
// 8.8%, Occ 9.7%). This version stages via REGISTERS: prefetch next-kt global
// loads before the MFMA phase; their vmcnt wait lands at the NEXT iteration's
// ds_write, i.e. after the MFMA block — overlap without fighting the
// compiler's barrier semantics. kt loop kept rolled so the unroller can't
// hoist all prefetch loads and re-spill (R5/R6: 291 MB scratch).
//
// LDS swizzle (numerics verified R7, absmax 0): row r, 16B chunk c at
// r*128 + (c^(r&7))*16. Now applied on the ds_write side too: staging thread
// t holds chunk (row = i*32 + t>>3, c = t&7) -> both writes and fragment
// reads are bank-conflict-free, and global reads are 128 B contiguous runs.
__global__ __launch_bounds__(256) void sim_k(const unsigned char* __restrict__ xn,
                                             float* __restrict__ sumexp,
                                             float* __restrict__ pos) {
  __shared__ unsigned char As[128 * 128];
  __shared__ unsigned char Bs[128 * 128];
  const int tid = threadIdx.x;
  const int l = tid & 63;
  const int m = l & 15, q = l >> 4, s = l & 7;
  const int wr = (tid >> 6) >> 1, wc = (tid >> 6) & 1;

  // triangular decode: bid -> (rt, ct), rt <= ct; start(r) = r*64 - r(r-1)/2
  const int bid = blockIdx.x;
  int rt = (int)((129.0f - sqrtf(16641.0f - 8.0f * (float)bid)) * 0.5f);
  rt = rt < 0 ? 0 : (rt > 63 ? 63 : rt);
  while (rt > 0 && (rt * 64 - rt * (rt - 1) / 2) > bid) --rt;
  while (rt < 63 && ((rt + 1) * 64 - (rt + 1) * rt / 2) <= bid) ++rt;
  const int ct = rt + (bid - (rt * 64 - rt * (rt - 1) / 2));
  const bool diag = (rt == ct);

  floatx4 acc[4][4] = {};

  const unsigned char* gA = xn + (size_t)rt * 128 * ND;
  const unsigned char* gB = xn + (size_t)ct * 128 * ND;

  // staging geometry: thread t, slab i: global (row i*32 + (t>>3),
  // bytes kt*128 + (t&7)*16 .. +16) -> LDS row*128 + ((t&7)^(row&7))*16
  const int crow = tid >> 3;
  const int coff = (tid & 7) * 16;
  const int lsw = ((tid & 7) ^ ((tid >> 3) & 7)) * 16;

  // fragment read offsets (swizzled): row l&15, k-chunks 2q, 2q+1
  const int fo0 = ((2 * q + 0) ^ s) * 16;
  const int fo1 = ((2 * q + 1) ^ s) * 16;

  int4v pA[4], pB[4];
#pragma unroll
  for (int i = 0; i < 4; ++i) {  // prologue: prefetch kt=0
    const size_t go = (size_t)(i * 32 + crow) * ND + coff;
    pA[i] = *(const int4v*)(gA + go);
    pB[i] = *(const int4v*)(gB + go);
  }

#pragma unroll 1  // rolled: prevents hoisting every kt's prefetch (re-spill)
  for (int kt = 0; kt < 4; ++kt) {
#pragma unroll
    for (int i = 0; i < 4; ++i) {  // stage current kt (vmcnt wait lands here)
      const int la = (i * 32 + crow) * 128 + lsw;
      *(int4v*)(As + la) = pA[i];
      *(int4v*)(Bs + la) = pB[i];
    }
    __syncthreads();
    if (kt < 3) {  // prefetch kt+1 — in flight across the MFMA phase below
      const int kb = (kt + 1) * 128;
#pragma unroll
      for (int i = 0; i < 4; ++i) {
        const size_t go = (size_t)(i * 32 + crow) * ND + kb + coff;
        pA[i] = *(const int4v*)(gA + go);
        pB[i] = *(const int4v*)(gB + go);
      }
    }
    int8v af0, af1, af2, af3, bf0, bf1, bf2, bf3;
    {
      const unsigned char* pa0 = As + (wr * 64 + 0 * 16 + m) * 128;
      const unsigned char* pa1 = As + (wr * 64 + 1 * 16 + m) * 128;
      const unsigned char* pa2 = As + (wr * 64 + 2 * 16 + m) * 128;
      const unsigned char* pa3 = As + (wr * 64 + 3 * 16 + m) * 128;
      const unsigned char* pb0 = Bs + (wc * 64 + 0 * 16 + m) * 128;
      const unsigned char* pb1 = Bs + (wc * 64 + 1 * 16 + m) * 128;
      const unsigned char* pb2 = Bs + (wc * 64 + 2 * 16 + m) * 128;
      const unsigned char* pb3 = Bs + (wc * 64 + 3 * 16 + m) * 128;
      af0 = __builtin_shufflevector(*(const int4v*)(pa0 + fo0),
                                    *(const int4v*)(pa0 + fo1), 0,1,2,3,4,5,6,7);
      af1 = __builtin_shufflevector(*(const int4v*)(pa1 + fo0),
                                    *(const int4v*)(pa1 + fo1), 0,1,2,3,4,5,6,7);
      af2 = __builtin_shufflevector(*(const int4v*)(pa2 + fo0),
                                    *(const int4v*)(pa2 + fo1), 0,1,2,3,4,5,6,7);
      af3 = __builtin_shufflevector(*(const int4v*)(pa3 + fo0),
                                    *(const int4v*)(pa3 + fo1), 0,1,2,3,4,5,6,7);
      bf0 = __builtin_shufflevector(*(const int4v*)(pb0 + fo0),
                                    *(const int4v*)(pb0 + fo1), 0,1,2,3,4,5,6,7);
      bf1 = __builtin_shufflevector(*(const int4v*)(pb1 + fo0),
                                    *(const int4v*)(pb1 + fo1), 0,1,2,3,4,5,6,7);
      bf2 = __builtin_shufflevector(*(const int4v*)(pb2 + fo0),
                                    *(const int4v*)(pb2 + fo1), 0,1,2,3,4,5,6,7);
      bf3 = __builtin_shufflevector(*(const int4v*)(pb3 + fo0),
                                    *(const int4v*)(pb3 + fo1), 0,1,2,3,4,5,6,7);
    }
#define MFMA_ROW(mt, afv)                                                     \
  acc[mt][0] = __builtin_amdgcn_mfma_scale_f32_16x16x128_f8f6f4(              \
      afv, bf0, acc[mt][0], 0, 0, 0, SCALE1, 0, SCALE1);                      \
  acc[mt][1] = __builtin_amdgcn_mfma_scale_f32_16x16x128_f8f6f4(              \
      afv, bf1, acc[mt][1], 0, 0, 0, SCALE1, 0, SCALE1);                      \
  acc[mt][2] = __builtin_amdgcn_mfma_scale_f32_16x16x128_f8f6f4(              \
      afv, bf2, acc[mt][2], 0, 0, 0, SCALE1, 0, SCALE1);                      \
  acc[mt][3] = __builtin_amdgcn_mfma_scale_f32_16x16x128_f8f6f4(              \
      afv, bf3, acc[mt][3], 0, 0, 0, SCALE1, 0, SCALE1)
    MFMA_ROW(0, af0);
    MFMA_ROW(1, af1);
    MFMA_ROW(2, af2);
    MFMA_ROW(3, af3);
#undef MFMA_ROW
    __syncthreads();  // all frag reads done before next kt's ds_writes
  }

  // epilogue: s = 2*acc; masked cols ((c-r)%B==0) store pos, skip sums.
  // Row sums always; col sums + pos mirror only on off-diagonal tiles.
  const int r0 = rt * 128 + wr * 64;
  const int c0 = ct * 128 + wc * 64;
  float cs[4] = {0.f, 0.f, 0.f, 0.f};  // per-nt column partials (this lane's q)
#pragma unroll
  for (int mt = 0; mt < 4; ++mt) {
    float rs[4] = {0.f, 0.f, 0.f, 0.f};
#pragma unroll
    for (int nt = 0; nt < 4; ++nt) {
      const int c = c0 + nt * 16 + m;  // C layout: col = lane&15
#pragma unroll
      for (int reg = 0; reg < 4; ++reg) {
        const int r = r0 + mt * 16 + q * 4 + reg;  // row = quad*4 + reg
        const float sv = acc[mt][nt][reg] * 2.0f;
        if (((c - r) & (NB - 1)) == 0) {
          pos[r * NV + (c >> 11)] = sv;  // includes j==i (unused later)
          if (!diag) pos[c * NV + (r >> 11)] = sv;
        } else {
          const float e = __expf(sv);
          rs[reg] += e;
          cs[nt] += e;
        }
      }
    }
    // reduce rows across the 16-lane column dimension (m)
#pragma unroll
    for (int off = 1; off < 16; off <<= 1) {
#pragma unroll
      for (int reg = 0; reg < 4; ++reg) rs[reg] += __shfl_xor(rs[reg], off, 64);
    }
    if (m < 4) atomicAdd(&sumexp[r0 + mt * 16 + q * 4 + m], rs[m]);
  }
  if (!diag) {
    // reduce cols across the 4-quad row dimension (q)
#pragma unroll
    for (int nt = 0; nt < 4; ++nt) {
      cs[nt] += __shfl_xor(cs[nt], 16, 64);
      cs[nt] += __shfl_xor(cs[nt], 32, 64);
    }
    if (q == 0) {
#pragma unroll
      for (int nt = 0; nt < 4; ++nt)
        atomicAdd(&sumexp[c0 + nt * 16 + m], cs[nt]);
    }
  }
}

// ---------------- finalize: scalar loss -------------------------------------
__global__ __launch_bounds__(256) void finalize_k(
    const float* __restrict__ sumexp, const float* __restrict__ pos,
    float* __restrict__ out) {
  const int r = blockIdx.x * 256 + threadIdx.x;
  const float se = sumexp[r];
  const int i = r >> 11;  // view index
  float local = 0.0f;
#pragma unroll
  for (int j = 0; j < NV; ++j) {
    if (j == i) continue;
    const float p = pos[r * NV + j];
    local += logf(__expf(p) + se) - p;  // logaddexp(pos, lse_neg) - pos
  }
  local *= (1.0f / NB);
#pragma unroll
  for (int off = 32; off > 0; off >>= 1) local += __shfl_xor(local, off, 64);
  if ((threadIdx.x & 63) == 0) atomicAdd(out, local);
}

extern "C" void kernel_launch(void* const* d_in, const int* in_sizes, int n_in,
                              void* d_out, int out_size, void* d_ws,
                              size_t ws_size, hipStream_t stream) {
  const float* x = (const float*)d_in[0];
  float* out = (float*)d_out;
  char* ws = (char*)d_ws;
  unsigned char* xn = (unsigned char*)ws;                 // 4 MB fp8
  float* sumexp = (float*)(ws + (size_t)NN * ND);         // 32 KB
  float* pos = (float*)(ws + (size_t)NN * ND + NN * 4);   // 128 KB

  normalize_k<<<NN / 4, 256, 0, stream>>>(x, xn, sumexp, out);
  sim_k<<<64 * 65 / 2, 256, 0, stream>>>(xn, sumexp, pos);
  finalize_k<<<NN / 256, 256, 0, stream>>>(sumexp, pos, out);
}